// Round 3
// baseline (381.843 us; speedup 1.0000x reference)
//
#include <hip/hip_runtime.h>
#include <math.h>

#define NBINS 36
#define HREP 4
#define HSTRIDE 38   // doubles; 38*8=304B -> replica bank offset 12, decorrelated

// Modified Bessel I_n(t) via the exact series the reference's iv() uses.
__device__ double bessel_iv(int n, double t) {
    double q = t * t * 0.25;
    double term = 1.0;
    for (int i = 1; i <= n; ++i) term *= (t * 0.5) / (double)i;  // (t/2)^n / n!
    double s = term;
    for (int k = 1; k <= 40; ++k) {
        term *= q / ((double)k * (double)(k + n));
        s += term;
    }
    return s;
}

__launch_bounds__(256)
__global__ void patch_orient_kernel(const float* __restrict__ in, float* __restrict__ out) {
    __shared__ float  p[32][36];            // patch, padded stride (16B-aligned rows)
    __shared__ double hist[HREP][HSTRIDE];  // per-wave replicated histograms
    __shared__ float  gtab[32];             // normalized 1D gaussian weight
    __shared__ double smk[3];               // smooth kernel [|n|=2, |n|=1, |n|=0]
    __shared__ double bins[NBINS];
    __shared__ double smv[NBINS];

    const int tid = threadIdx.x;
    const int bid = blockIdx.x;
    const int wv  = tid >> 6;

    // ---- stage patch into LDS (coalesced float4) ----
    {
        const float4 v = reinterpret_cast<const float4*>(in + (size_t)bid * 1024)[tid];
        const int row = tid >> 3;
        const int col = (tid & 7) << 2;
        *reinterpret_cast<float4*>(&p[row][col]) = v;
    }

    // ---- zero histograms ----
    if (tid < HREP * HSTRIDE) reinterpret_cast<double*>(hist)[tid] = 0.0;

    // ---- per-block constant tables (f64, matching reference's host-side math) ----
    if (tid < 32) {
        double x = (double)tid - 15.5;                     // even ksize: +0.5 offset
        double e = exp(-x * x / 56.888888888888886);       // 2*sigma^2, sigma=32/6
        double s = e;
        #pragma unroll
        for (int o = 16; o >= 1; o >>= 1) s += __shfl_xor(s, o);
        gtab[tid] = (float)(e / s);                        // outer(g,g) == gn[y]*gn[x]
    }
    if (tid == 0) {
        const double t = 1.6 * 1.6;                        // sigma^2 = 2.56
        double I0 = bessel_iv(0, t);
        double I1 = bessel_iv(1, t);
        double I2 = bessel_iv(2, t);
        double S  = I0 + 2.0 * (I1 + I2);                  // exp(-t) cancels
        smk[0] = I2 / S; smk[1] = I1 / S; smk[2] = I0 / S;
    }
    __syncthreads();

    // ---- per-thread: 4 consecutive pixels in one row ----
    const int y  = tid >> 3;
    const int x0 = (tid & 7) << 2;
    const int ym = (y == 0)  ? 0  : y - 1;
    const int yp = (y == 31) ? 31 : y + 1;

    float r0[6], r1[6], r2[6];
    {
        const float* a = p[ym];
        const float* b = p[y];
        const float* c = p[yp];
        const int xl = (x0 == 0)  ? 0  : x0 - 1;
        const int xr = (x0 == 28) ? 31 : x0 + 4;
        float4 a4 = *reinterpret_cast<const float4*>(a + x0);
        float4 b4 = *reinterpret_cast<const float4*>(b + x0);
        float4 c4 = *reinterpret_cast<const float4*>(c + x0);
        r0[0] = a[xl]; r0[1] = a4.x; r0[2] = a4.y; r0[3] = a4.z; r0[4] = a4.w; r0[5] = a[xr];
        r1[0] = b[xl]; r1[1] = b4.x; r1[2] = b4.y; r1[3] = b4.z; r1[4] = b4.w; r1[5] = b[xr];
        r2[0] = c[xl]; r2[1] = c4.x; r2[2] = c4.y; r2[3] = c4.z; r2[4] = c4.w; r2[5] = c[xr];
    }

    double* h = hist[wv];
    const float gw_y = gtab[y];
    #pragma unroll
    for (int i = 0; i < 4; ++i) {
        float gx = (r0[i+2] - r0[i] + 2.0f * (r1[i+2] - r1[i]) + r2[i+2] - r2[i]) * 0.125f;
        float gy = (r2[i] + 2.0f * r2[i+1] + r2[i+2] - r0[i] - 2.0f * r0[i+1] - r0[i+2]) * 0.125f;
        float w   = gw_y * gtab[x0 + i];
        float mag = sqrtf(gx * gx + gy * gy + 1e-8f) * w;
        float ori = atan2f(gy, gx + 1e-8f) + 6.2831855f;          // + 2*pi
        float ob  = ((ori + 3.1415927f) * 36.0f) / 6.2831855f;    // NUM_BINS*(ori+pi)/(2pi)
        float bo0 = floorf(ob);
        float wo1 = ob - bo0;
        int ib = (int)bo0 - 36;                                   // nominal [0,36]; f32 edge: [-1,37]
        int b0 = (ib < 0) ? ib + 36 : ((ib >= 36) ? ib - 36 : ib);  // proper wrap (bo0 % 36)
        int b1 = (b0 + 1 >= 36) ? 0 : b0 + 1;
        atomicAdd(&h[b0], (double)((1.0f - wo1) * mag));
        atomicAdd(&h[b1], (double)(wo1 * mag));
    }
    __syncthreads();

    // ---- reduce replicas, /HW ----
    if (tid < NBINS) {
        double v = (hist[0][tid] + hist[1][tid] + hist[2][tid] + hist[3][tid]) * (1.0 / 1024.0);
        bins[tid] = v;
    }
    __syncthreads();

    // ---- circular 5-tap smooth ----
    if (tid < NBINS) {
        int tm2 = tid - 2; if (tm2 < 0) tm2 += 36;
        int tm1 = tid - 1; if (tm1 < 0) tm1 += 36;
        int tp1 = tid + 1; if (tp1 >= 36) tp1 -= 36;
        int tp2 = tid + 2; if (tp2 >= 36) tp2 -= 36;
        smv[tid] = smk[0] * bins[tm2] + smk[1] * bins[tm1] + smk[2] * bins[tid]
                 + smk[1] * bins[tp1] + smk[0] * bins[tp2];
    }
    __syncthreads();

    // ---- argmax (first occurrence) + subpixel, wave 0 only ----
    if (tid < 64) {
        double v  = (tid < NBINS) ? smv[tid] : -1.0e300;
        int   idx = tid;
        #pragma unroll
        for (int o = 32; o >= 1; o >>= 1) {
            double ov = __shfl_xor(v, o);
            int    oi = __shfl_xor(idx, o);
            if (ov > v || (ov == v && oi < idx)) { v = ov; idx = oi; }
        }
        if (tid == 0) {
            int il = idx - 1; if (il < 0) il += 36;
            int ir = idx + 1; if (ir >= 36) ir -= 36;
            double l = smv[il], r = smv[ir];
            double c = 0.5 * (l - r) / (l + r - 2.0 * v);
            double ang = -(6.283185307179586 * ((double)idx + c) / 36.0 - 3.141592653589793);
            out[bid] = (float)ang;
        }
    }
}

extern "C" void kernel_launch(void* const* d_in, const int* in_sizes, int n_in,
                              void* d_out, int out_size, void* d_ws, size_t ws_size,
                              hipStream_t stream) {
    const float* patch = (const float*)d_in[0];
    float* out = (float*)d_out;
    const int B = in_sizes[0] >> 10;  // 32768 patches of 1024 px
    patch_orient_kernel<<<B, 256, 0, stream>>>(patch, out);
}

// Round 4
// 226.412 us; speedup vs baseline: 1.6865x; 1.6865x over previous
//
#include <hip/hip_runtime.h>
#include <math.h>

#define NBINS 36
#define PSTRIDE 44        // patch row stride in LDS words: 176B, 16B-aligned, 12-bank skew
#define HREP 8            // one histogram replica per half-wave
#define HSTRIDE 40

// ---- one-block setup: builds gaussian weight table + smooth kernel in f64 (ref-exact) ----
__global__ __launch_bounds__(64) void setup_tables(double* __restrict__ smkws,
                                                   float* __restrict__ gws) {
    if (threadIdx.x == 0) {
        double s = 0.0;
        for (int i = 0; i < 32; ++i) {
            double x = (double)i - 15.5;
            s += exp(-x * x / 56.888888888888886);     // 2*sigma^2, sigma=32/6
        }
        for (int i = 0; i < 32; ++i) {
            double x = (double)i - 15.5;
            gws[i] = (float)(exp(-x * x / 56.888888888888886) / s);
        }
        // discrete-gaussian smooth kernel via the reference's Bessel series, t = 1.6^2
        const double t = 2.56;
        double I[3];
        for (int n = 0; n < 3; ++n) {
            double q = t * t * 0.25;
            double term = 1.0;
            for (int i = 1; i <= n; ++i) term *= (t * 0.5) / (double)i;
            double acc = term;
            for (int k = 1; k <= 40; ++k) { term *= q / ((double)k * (double)(k + n)); acc += term; }
            I[n] = acc;
        }
        double S = I[0] + 2.0 * (I[1] + I[2]);          // exp(-t) cancels in normalization
        smkws[0] = I[2] / S; smkws[1] = I[1] / S; smkws[2] = I[0] / S;
    }
}

__launch_bounds__(256)
__global__ void patch_orient_kernel(const float* __restrict__ in, float* __restrict__ out,
                                    const double* __restrict__ smkws,
                                    const float* __restrict__ gws) {
    __shared__ __align__(16) float p[32 * PSTRIDE];
    __shared__ unsigned hist[HREP * HSTRIDE];
    __shared__ __align__(16) float gtab[32];
    __shared__ double binsd[NBINS];
    __shared__ double smv[NBINS];

    const int tid = threadIdx.x;
    const int bid = blockIdx.x;

    // ---- stage patch (coalesced float4), zero histograms, load weight table ----
    {
        const float4 v = reinterpret_cast<const float4*>(in + (size_t)bid * 1024)[tid];
        const int row = tid >> 3, col = (tid & 7) << 2;
        *reinterpret_cast<float4*>(&p[row * PSTRIDE + col]) = v;
    }
    if (tid < 32) gtab[tid] = gws[tid];
    hist[tid] = 0u;
    if (tid < HREP * HSTRIDE - 256) hist[256 + tid] = 0u;
    __syncthreads();

    // ---- per-thread: 4 consecutive pixels in one row; separable Sobel ----
    const int y  = tid >> 3;
    const int x0 = (tid & 7) << 2;
    const float* A = &p[((y == 0)  ? 0  : y - 1) * PSTRIDE];
    const float* Bv = &p[y * PSTRIDE];
    const float* C = &p[((y == 31) ? 31 : y + 1) * PSTRIDE];
    const int xl = (x0 == 0)  ? 0  : x0 - 1;
    const int xr = (x0 == 28) ? 31 : x0 + 4;

    float s[6], d[6];
    {
        float4 a4 = *reinterpret_cast<const float4*>(A + x0);
        float4 b4 = *reinterpret_cast<const float4*>(Bv + x0);
        float4 c4 = *reinterpret_cast<const float4*>(C + x0);
        float al = A[xl], bl = Bv[xl], cl = C[xl];
        float ar = A[xr], br = Bv[xr], cr = C[xr];
        s[0] = fmaf(2.f, bl,   al)   + cl;   d[0] = cl   - al;
        s[1] = fmaf(2.f, b4.x, a4.x) + c4.x; d[1] = c4.x - a4.x;
        s[2] = fmaf(2.f, b4.y, a4.y) + c4.y; d[2] = c4.y - a4.y;
        s[3] = fmaf(2.f, b4.z, a4.z) + c4.z; d[3] = c4.z - a4.z;
        s[4] = fmaf(2.f, b4.w, a4.w) + c4.w; d[4] = c4.w - a4.w;
        s[5] = fmaf(2.f, br,   ar)   + cr;   d[5] = cr   - ar;
    }

    unsigned* h = &hist[(tid >> 5) * HSTRIDE];   // per-half-wave replica
    const float gwy = gtab[y];
    const float4 gx4 = *reinterpret_cast<const float4*>(&gtab[x0]);
    const float gw[4] = {gx4.x, gx4.y, gx4.z, gx4.w};

    #pragma unroll
    for (int i = 0; i < 4; ++i) {
        float gx = (s[i + 2] - s[i]) * 0.125f;
        float gy = (fmaf(2.f, d[i + 1], d[i]) + d[i + 2]) * 0.125f;
        float w  = gwy * gw[i];
        float m2 = fmaf(gx, gx, fmaf(gy, gy, 1e-8f));
        float mag = m2 * __builtin_amdgcn_rsqf(m2) * w;      // sqrt(m2)*w
        float xx = gx + 1e-8f;
        // --- branchless atan2 (cephes-grade, err ~2e-7) ---
        float ax = fabsf(xx), ay = fabsf(gy);
        float hi = fmaxf(ax, ay), lo = fminf(ax, ay);
        float hs = (hi == 0.f) ? 1.f : hi;
        float t  = lo * __builtin_amdgcn_rcpf(hs);           // [0,1]
        float rn = (t - 1.f) * __builtin_amdgcn_rcpf(t + 1.f);
        bool  red = t > 0.41421356f;                         // tan(pi/8)
        float u    = red ? rn : t;                           // [-0.414, 0.414]
        float base = red ? 0.78539816339f : 0.f;
        float z = u * u;
        float pl = fmaf(fmaf(fmaf(8.05374449538e-2f, z, -1.38776856032e-1f), z,
                              1.99777106478e-1f), z, -3.33329491539e-1f);
        float th = fmaf(pl * z, u, u) + base;                // atan(lo/hi)
        th = (ay > ax)  ? (1.57079632679f - th) : th;
        th = (xx < 0.f) ? (3.14159265359f - th) : th;
        th = (gy < 0.f) ? -th : th;
        // --- binning: o_big = th*36/(2pi) + 54  in (36, 72] ---
        float ob  = fmaf(th, 5.72957795131f, 54.f);
        float bo0 = floorf(ob);
        float wo1 = ob - bo0;
        int ib = (int)bo0 - 36;                              // nominal [0,36]; f32 edge [-1,37]
        int b0 = ib < 0 ? ib + 36 : (ib >= 36 ? ib - 36 : ib);
        int b1 = (b0 + 1 >= 36) ? 0 : b0 + 1;
        float w1f = wo1 * mag;
        float w0f = (1.f - wo1) * mag;
        // fixed-point ds_add_u32: scale 2^30; order-independent => deterministic
        atomicAdd(&h[b0], (unsigned)fmaf(w0f, 1073741824.f, 0.5f));
        atomicAdd(&h[b1], (unsigned)fmaf(w1f, 1073741824.f, 0.5f));
    }
    __syncthreads();

    // ---- wave 0 only from here (exact u32 sums -> f64; all deterministic) ----
    if (tid < NBINS) {
        unsigned acc = 0;
        #pragma unroll
        for (int r = 0; r < HREP; ++r) acc += hist[r * HSTRIDE + tid];
        binsd[tid] = (double)acc;
    }
    if (tid < NBINS) {
        double k2 = smkws[0], k1 = smkws[1], k0 = smkws[2];
        int tm2 = tid - 2; if (tm2 < 0) tm2 += 36;
        int tm1 = tid - 1; if (tm1 < 0) tm1 += 36;
        int tp1 = tid + 1; if (tp1 >= 36) tp1 -= 36;
        int tp2 = tid + 2; if (tp2 >= 36) tp2 -= 36;
        smv[tid] = k2 * binsd[tm2] + k1 * binsd[tm1] + k0 * binsd[tid]
                 + k1 * binsd[tp1] + k2 * binsd[tp2];
    }
    if (tid < 64) {
        double v  = (tid < NBINS) ? smv[tid] : -1.0e300;
        int   idx = tid;
        #pragma unroll
        for (int o = 32; o >= 1; o >>= 1) {
            double ov = __shfl_xor(v, o);
            int    oi = __shfl_xor(idx, o);
            if (ov > v || (ov == v && oi < idx)) { v = ov; idx = oi; }
        }
        if (tid == 0) {
            int il = idx - 1; if (il < 0) il += 36;
            int ir = idx + 1; if (ir >= 36) ir -= 36;
            double l = smv[il], r = smv[ir];
            double c = 0.5 * (l - r) / (l + r - 2.0 * v);
            double ang = -(6.283185307179586 * ((double)idx + c) / 36.0 - 3.141592653589793);
            out[bid] = (float)ang;
        }
    }
}

extern "C" void kernel_launch(void* const* d_in, const int* in_sizes, int n_in,
                              void* d_out, int out_size, void* d_ws, size_t ws_size,
                              hipStream_t stream) {
    const float* patch = (const float*)d_in[0];
    float* out = (float*)d_out;
    double* smkws = (double*)d_ws;                       // 3 doubles @ 0
    float*  gws   = (float*)((char*)d_ws + 32);          // 32 floats @ 32
    const int B = in_sizes[0] >> 10;                     // 32768 patches
    setup_tables<<<1, 64, 0, stream>>>(smkws, gws);
    patch_orient_kernel<<<B, 256, 0, stream>>>(patch, out, smkws, gws);
}

// Round 5
// 206.762 us; speedup vs baseline: 1.8468x; 1.0950x over previous
//
#include <hip/hip_runtime.h>
#include <math.h>

#define NBINS 36
#define PSTRIDE 44        // patch row stride in LDS words: 176B, 16B-aligned, 12-bank skew
#define HREP 16           // one histogram replica per 16 lanes
#define HSTRIDE 40        // 38 slots used (36 bins + 2 alias), stride 40

// ---- one-block setup: gaussian weight table (pre-scaled) + smooth kernel, parallel ----
__global__ __launch_bounds__(64) void setup_tables(double* __restrict__ smkws,
                                                   float* __restrict__ gws) {
    const int t = threadIdx.x;
    if (t < 32) {
        double x = (double)t - 15.5;
        double e = exp(-x * x / 56.888888888888886);     // 2*sigma^2, sigma=32/6
        double s = e;
        #pragma unroll
        for (int o = 16; o >= 1; o >>= 1) s += __shfl_xor(s, o);
        // scale = 2^15 / sqrt(8): bakes the /8 Sobel norm and 2^30 fixed-point into w=gy*gx
        gws[t] = (float)((e / s) * 11585.237502960395);
    }
    if (t < 3) {   // thread n computes Bessel I_n(t=2.56) via the reference's series
        const double tt = 2.56;
        double q = tt * tt * 0.25;
        double term = 1.0;
        for (int i = 1; i <= t; ++i) term *= (tt * 0.5) / (double)i;
        double acc = term;
        for (int k = 1; k <= 40; ++k) { term *= q / ((double)k * (double)(k + t)); acc += term; }
        double I0 = __shfl(acc, 0), I1 = __shfl(acc, 1), I2 = __shfl(acc, 2);
        double S  = I0 + 2.0 * (I1 + I2);                // exp(-t) cancels
        smkws[t] = acc / S;                              // [0]=center,[1]=mid,[2]=outer
    }
}

__launch_bounds__(256)
__global__ void patch_orient_kernel(const float* __restrict__ in, float* __restrict__ out,
                                    const double* __restrict__ smkws,
                                    const float* __restrict__ gws) {
    __shared__ __align__(16) float p[32 * PSTRIDE];
    __shared__ unsigned hist[HREP * HSTRIDE];
    __shared__ __align__(16) float gtab[32];
    __shared__ double binsd[NBINS];
    __shared__ double smv[NBINS];

    const int tid = threadIdx.x;
    const int bid = blockIdx.x;

    // ---- stage patch (coalesced float4), zero histograms, load weight table ----
    {
        const float4 v = reinterpret_cast<const float4*>(in + (size_t)bid * 1024)[tid];
        const int row = tid >> 3, col = (tid & 7) << 2;
        *reinterpret_cast<float4*>(&p[row * PSTRIDE + col]) = v;
    }
    if (tid < 32) gtab[tid] = gws[tid];
    hist[tid] = 0u;
    hist[tid + 256] = 0u;
    if (tid < HREP * HSTRIDE - 512) hist[tid + 512] = 0u;
    __syncthreads();

    // ---- per-thread: 4 consecutive pixels in one row; separable Sobel (unnormalized) ----
    const int y  = tid >> 3;
    const int x0 = (tid & 7) << 2;
    const float* A  = &p[((y == 0)  ? 0  : y - 1) * PSTRIDE];
    const float* Bv = &p[y * PSTRIDE];
    const float* C  = &p[((y == 31) ? 31 : y + 1) * PSTRIDE];
    const int xl = (x0 == 0)  ? 0  : x0 - 1;
    const int xr = (x0 == 28) ? 31 : x0 + 4;

    float s[6], d[6];
    {
        float4 a4 = *reinterpret_cast<const float4*>(A + x0);
        float4 b4 = *reinterpret_cast<const float4*>(Bv + x0);
        float4 c4 = *reinterpret_cast<const float4*>(C + x0);
        float al = A[xl], bl = Bv[xl], cl = C[xl];
        float ar = A[xr], br = Bv[xr], cr = C[xr];
        s[0] = fmaf(2.f, bl,   al)   + cl;   d[0] = cl   - al;
        s[1] = fmaf(2.f, b4.x, a4.x) + c4.x; d[1] = c4.x - a4.x;
        s[2] = fmaf(2.f, b4.y, a4.y) + c4.y; d[2] = c4.y - a4.y;
        s[3] = fmaf(2.f, b4.z, a4.z) + c4.z; d[3] = c4.z - a4.z;
        s[4] = fmaf(2.f, b4.w, a4.w) + c4.w; d[4] = c4.w - a4.w;
        s[5] = fmaf(2.f, br,   ar)   + cr;   d[5] = cr   - ar;
    }

    unsigned* h = &hist[(tid >> 4) * HSTRIDE];   // per-16-lane replica
    const float gwy = gtab[y];
    const float4 gx4 = *reinterpret_cast<const float4*>(&gtab[x0]);
    const float gw[4] = {gx4.x, gx4.y, gx4.z, gx4.w};

    #pragma unroll
    for (int i = 0; i < 4; ++i) {
        float gx8 = s[i + 2] - s[i];                          // 8*gx
        float gy8 = fmaf(2.f, d[i + 1], d[i]) + d[i + 2];     // 8*gy
        float m2  = fmaf(gx8, gx8, fmaf(gy8, gy8, 6.4e-7f));  // 64*(gx^2+gy^2+1e-8)
        float w   = gwy * gw[i];                              // g_y*g_x * 2^30/8
        float mag = m2 * __builtin_amdgcn_rsqf(m2) * w;       // ref_mag * 2^30
        float xx  = gx8 + 8e-8f;                              // 8*(gx+1e-8): same sign/ratio
        // --- atan2 in BIN units: deg-15 odd minimax of atan on [0,1], coeffs *36/(2pi) ---
        float ax = fabsf(xx), ay = fabsf(gy8);
        float hi = fmaxf(ax, ay), lo = fminf(ax, ay);
        float t  = lo * __builtin_amdgcn_rcpf(fmaxf(hi, 1e-37f));   // [0,1]
        float z  = t * t;
        float pz = fmaf(fmaf(fmaf(fmaf(fmaf(fmaf(fmaf(
                   -2.32279295e-2f, z,  1.25257116e-1f), z, -3.20340049e-1f), z,
                    5.52446198e-1f), z, -7.96900272e-1f), z,  1.14285232f),  z,
                   -1.90966007f),    z,  5.72957413f);
        float th = t * pz;                                    // atan(lo/hi) in bins [0,4.5]
        th = (ay  > ax)  ? ( 9.f - th) : th;
        th = (xx  < 0.f) ? (18.f - th) : th;
        th = (gy8 < 0.f) ? -th : th;                          // [-18,18]
        float ob  = th + 18.f;                                // [0,36]
        int   ib  = (int)ob;                                  // trunc==floor (ob>=0); [0,36]
        float wo1 = ob - (float)ib;
        float w1  = wo1 * mag;
        float w0  = mag - w1;
        // bins 36,37 are aliases of 0,1 — folded at reduce time (no per-pixel wrap)
        atomicAdd(&h[ib],     (unsigned)w0);
        atomicAdd(&h[ib + 1], (unsigned)w1);
    }
    __syncthreads();

    // ---- wave 0 only: fold aliases, exact u32 sums -> f64 (deterministic) ----
    if (tid < NBINS) {
        unsigned acc = 0;
        #pragma unroll
        for (int r = 0; r < HREP; ++r) acc += hist[r * HSTRIDE + tid];
        if (tid < 2) {
            #pragma unroll
            for (int r = 0; r < HREP; ++r) acc += hist[r * HSTRIDE + NBINS + tid];
        }
        binsd[tid] = (double)acc;
    }
    if (tid < NBINS) {
        double k0 = smkws[0], k1 = smkws[1], k2 = smkws[2];   // center, mid, outer
        int tm2 = tid - 2; if (tm2 < 0) tm2 += 36;
        int tm1 = tid - 1; if (tm1 < 0) tm1 += 36;
        int tp1 = tid + 1; if (tp1 >= 36) tp1 -= 36;
        int tp2 = tid + 2; if (tp2 >= 36) tp2 -= 36;
        smv[tid] = k2 * binsd[tm2] + k1 * binsd[tm1] + k0 * binsd[tid]
                 + k1 * binsd[tp1] + k2 * binsd[tp2];
    }
    if (tid < 64) {
        double v  = (tid < NBINS) ? smv[tid] : -1.0e300;
        int   idx = tid;
        #pragma unroll
        for (int o = 32; o >= 1; o >>= 1) {
            double ov = __shfl_xor(v, o);
            int    oi = __shfl_xor(idx, o);
            if (ov > v || (ov == v && oi < idx)) { v = ov; idx = oi; }
        }
        if (tid == 0) {
            int il = idx - 1; if (il < 0) il += 36;
            int ir = idx + 1; if (ir >= 36) ir -= 36;
            double l = smv[il], r = smv[ir];
            double c = 0.5 * (l - r) / (l + r - 2.0 * v);
            double ang = -(6.283185307179586 * ((double)idx + c) / 36.0 - 3.141592653589793);
            out[bid] = (float)ang;
        }
    }
}

extern "C" void kernel_launch(void* const* d_in, const int* in_sizes, int n_in,
                              void* d_out, int out_size, void* d_ws, size_t ws_size,
                              hipStream_t stream) {
    const float* patch = (const float*)d_in[0];
    float* out = (float*)d_out;
    double* smkws = (double*)d_ws;                       // 3 doubles @ 0
    float*  gws   = (float*)((char*)d_ws + 32);          // 32 floats @ 32
    const int B = in_sizes[0] >> 10;                     // 32768 patches
    setup_tables<<<1, 64, 0, stream>>>(smkws, gws);
    patch_orient_kernel<<<B, 256, 0, stream>>>(patch, out, smkws, gws);
}